// Round 18
// baseline (2924.115 us; speedup 1.0000x reference)
//
#include <hip/hip_runtime.h>

#define B_DIM 64
#define T_DIM 2048
#define F_DIM 512
#define H_DIM 128
#define G_DIM 384  // 3*H

typedef _Float16 half2_t __attribute__((ext_vector_type(2)));
typedef _Float16 f16x8   __attribute__((ext_vector_type(8)));
typedef unsigned int uint32;
typedef uint32 u32x4 __attribute__((ext_vector_type(4)));
typedef short bf16x8 __attribute__((ext_vector_type(8)));
typedef float f32x4  __attribute__((ext_vector_type(4)));

__device__ __forceinline__ float sigmoid_f(float x) {
    return __fdividef(1.0f, 1.0f + __expf(-x));
}
__device__ __forceinline__ float tanh_f(float x) {
    return __fdividef(2.0f, 1.0f + __expf(-2.0f * x)) - 1.0f;
}

__device__ __forceinline__ uint32 packf16(float a, float b) {
    half2_t p; p.x = (_Float16)a; p.y = (_Float16)b;
    return __builtin_bit_cast(uint32, p);
}

__device__ __forceinline__ uint32 pk_bf16(float lo, float hi) {
    uint32 r;
    asm("v_cvt_pk_bf16_f32 %0, %1, %2" : "=v"(r) : "v"(lo), "v"(hi));
    return r;
}

// Minimal barrier (R16/R17: equal to __syncthreads in perf; kept for the
// lgkmcnt-only semantics). Scan cross-wave traffic is LDS-only.
#define FAST_BARRIER()                                                            \
    __builtin_amdgcn_sched_barrier(0);                                            \
    asm volatile("s_waitcnt lgkmcnt(0)" ::: "memory");                            \
    __builtin_amdgcn_s_barrier();                                                 \
    __builtin_amdgcn_sched_barrier(0);

// ---------------------------------------------------------------------------
// Wcomb = w_ih0 @ w_proj  ([384,128]@[128,512] -> [384,512], fp32) and
// bcomb = w_ih0 @ b_proj + b_ih0. One-time 25 MF precompute: folds the
// projection GEMM into the layer-0 gate GEMM (gx0 = x @ Wcomb^T + bcomb).
// ---------------------------------------------------------------------------
__global__ __launch_bounds__(256)
void wcomb_kernel(const float* __restrict__ wih0, const float* __restrict__ wproj,
                  const float* __restrict__ bproj, const float* __restrict__ bih0,
                  float* __restrict__ Wcomb, float* __restrict__ bcomb)
{
    int gid = blockIdx.x * 256 + threadIdx.x;   // 0..49151
    int o   = gid >> 7;                         // 0..383
    int f0  = (gid & 127) * 4;
    float4 acc = {0.f, 0.f, 0.f, 0.f};
    for (int h = 0; h < H_DIM; ++h) {
        float w = wih0[o * H_DIM + h];
        float4 p = *(const float4*)&wproj[(size_t)h * F_DIM + f0];
        acc.x = fmaf(w, p.x, acc.x); acc.y = fmaf(w, p.y, acc.y);
        acc.z = fmaf(w, p.z, acc.z); acc.w = fmaf(w, p.w, acc.w);
    }
    *(float4*)&Wcomb[(size_t)o * F_DIM + f0] = acc;
    if ((gid & 127) == 0) {
        float s = bih0[o];
        for (int h = 0; h < H_DIM; ++h)
            s = fmaf(wih0[o * H_DIM + h], bproj[h], s);
        bcomb[o] = s;
    }
}

// ---------------------------------------------------------------------------
// bf16 MFMA GEMM (R10-proven): C[M x NDIM] = A @ W^T + bias; optional lengths.
// ---------------------------------------------------------------------------
template<int KDIM, int NDIM, bool DO_LEN>
__global__ __launch_bounds__(256)
void gemm_mfma_kernel(const float* __restrict__ A, const float* __restrict__ W,
                      const float* __restrict__ bias, float* __restrict__ C,
                      int* __restrict__ lengths)
{
    constexpr int KSTEPS = KDIM / 32;
    constexpr int PAD = 40;
    __shared__ __align__(16) unsigned short At[128 * PAD];
    __shared__ __align__(16) unsigned short Bt[128 * PAD];

    const int tid = threadIdx.x;
    const int m0  = blockIdx.x * 128;
    const int n0  = blockIdx.y * 128;
    const int row = tid >> 1;
    const int kh  = tid & 1;

    const float* Ap = A + (size_t)(m0 + row) * KDIM + kh * 16;
    const float* Wp = W + (size_t)(n0 + row) * KDIM + kh * 16;

    float4 aPre[4], bPre[4];
#pragma unroll
    for (int q = 0; q < 4; ++q) {
        aPre[q] = *(const float4*)(Ap + q * 4);
        bPre[q] = *(const float4*)(Wp + q * 4);
    }

    f32x4 acc[4][4];
#pragma unroll
    for (int i = 0; i < 4; ++i)
#pragma unroll
        for (int j = 0; j < 4; ++j) acc[i][j] = (f32x4){0.f, 0.f, 0.f, 0.f};

    const int wv = tid >> 6;
    const int wm = (wv >> 1) * 64;
    const int wn = (wv & 1) * 64;
    const int ln = tid & 63;
    const int fr = ln & 15;
    const int fq = ln >> 4;

    float rowsum = 0.0f;

    for (int ks = 0; ks < KSTEPS; ++ks) {
        if (DO_LEN) {
#pragma unroll
            for (int q = 0; q < 4; ++q)
                rowsum += aPre[q].x + aPre[q].y + aPre[q].z + aPre[q].w;
        }
        {
            uint32* ad = (uint32*)&At[row * PAD + kh * 16];
            uint32* bd = (uint32*)&Bt[row * PAD + kh * 16];
            uint4 au, bu;
            au.x = pk_bf16(aPre[0].x, aPre[0].y); au.y = pk_bf16(aPre[0].z, aPre[0].w);
            au.z = pk_bf16(aPre[1].x, aPre[1].y); au.w = pk_bf16(aPre[1].z, aPre[1].w);
            *(uint4*)ad = au;
            au.x = pk_bf16(aPre[2].x, aPre[2].y); au.y = pk_bf16(aPre[2].z, aPre[2].w);
            au.z = pk_bf16(aPre[3].x, aPre[3].y); au.w = pk_bf16(aPre[3].z, aPre[3].w);
            *(uint4*)(ad + 4) = au;
            bu.x = pk_bf16(bPre[0].x, bPre[0].y); bu.y = pk_bf16(bPre[0].z, bPre[0].w);
            bu.z = pk_bf16(bPre[1].x, bPre[1].y); bu.w = pk_bf16(bPre[1].z, bPre[1].w);
            *(uint4*)bd = bu;
            bu.x = pk_bf16(bPre[2].x, bPre[2].y); bu.y = pk_bf16(bPre[2].z, bPre[2].w);
            bu.z = pk_bf16(bPre[3].x, bPre[3].y); bu.w = pk_bf16(bPre[3].z, bPre[3].w);
            *(uint4*)(bd + 4) = bu;
        }
        __syncthreads();
        if (ks + 1 < KSTEPS) {
#pragma unroll
            for (int q = 0; q < 4; ++q) {
                aPre[q] = *(const float4*)(Ap + (ks + 1) * 32 + q * 4);
                bPre[q] = *(const float4*)(Wp + (ks + 1) * 32 + q * 4);
            }
        }
        bf16x8 aF[4], bF[4];
#pragma unroll
        for (int i = 0; i < 4; ++i) {
            aF[i] = *(const bf16x8*)&At[(wm + i * 16 + fr) * PAD + fq * 8];
            bF[i] = *(const bf16x8*)&Bt[(wn + i * 16 + fr) * PAD + fq * 8];
        }
#pragma unroll
        for (int i = 0; i < 4; ++i)
#pragma unroll
            for (int j = 0; j < 4; ++j)
                acc[i][j] = __builtin_amdgcn_mfma_f32_16x16x32_bf16(
                                aF[i], bF[j], acc[i][j], 0, 0, 0);
        __syncthreads();
    }

#pragma unroll
    for (int i = 0; i < 4; ++i) {
#pragma unroll
        for (int j = 0; j < 4; ++j) {
            const int n = n0 + wn + j * 16 + fr;
            const float bn = bias[n];
            const int mbase = m0 + wm + i * 16 + fq * 4;
#pragma unroll
            for (int r = 0; r < 4; ++r)
                C[(size_t)(mbase + r) * NDIM + n] = acc[i][j][r] + bn;
        }
    }

    if (DO_LEN && blockIdx.y == 0) {
        rowsum += __shfl_xor(rowsum, 1);
        if (kh == 0 && rowsum != 0.0f)
            atomicAdd(&lengths[(m0 + row) >> 11], 1);
    }
}

// ---------------------------------------------------------------------------
// Barrier-minimal MFMA GRU scan (R16-proven). One block per batch element,
// 512 threads = 8 waves. Wave w owns j in [w*16, w*16+16): 12 chained
// mfma_f32_16x16x32_f16 (A = h broadcast) give every lane the complete K=128
// dot for its (j, gate) in acc[0]. Redundant gate math across fq replicas;
// fq==0 writes h' f16. ONE barrier per step. 48 resident u32 weights.
// ---------------------------------------------------------------------------
#define SCAN_STEP(PR, CXR, CXZ, CXN)                                              \
    {                                                                             \
        const _Float16* hb = (const _Float16*)&hbuf[PR][0];                       \
        f16x8 ha0 = *(const f16x8*)(hb + 0 * 32 + fq * 8);                        \
        f16x8 ha1 = *(const f16x8*)(hb + 1 * 32 + fq * 8);                        \
        f16x8 ha2 = *(const f16x8*)(hb + 2 * 32 + fq * 8);                        \
        f16x8 ha3 = *(const f16x8*)(hb + 3 * 32 + fq * 8);                        \
        f32x4 accr = (f32x4){0.f,0.f,0.f,0.f};                                    \
        f32x4 accz = (f32x4){0.f,0.f,0.f,0.f};                                    \
        f32x4 accn = (f32x4){0.f,0.f,0.f,0.f};                                    \
        accr = __builtin_amdgcn_mfma_f32_16x16x32_f16(ha0, wR0, accr, 0, 0, 0);   \
        accz = __builtin_amdgcn_mfma_f32_16x16x32_f16(ha0, wZ0, accz, 0, 0, 0);   \
        accn = __builtin_amdgcn_mfma_f32_16x16x32_f16(ha0, wN0, accn, 0, 0, 0);   \
        accr = __builtin_amdgcn_mfma_f32_16x16x32_f16(ha1, wR1, accr, 0, 0, 0);   \
        accz = __builtin_amdgcn_mfma_f32_16x16x32_f16(ha1, wZ1, accz, 0, 0, 0);   \
        accn = __builtin_amdgcn_mfma_f32_16x16x32_f16(ha1, wN1, accn, 0, 0, 0);   \
        accr = __builtin_amdgcn_mfma_f32_16x16x32_f16(ha2, wR2, accr, 0, 0, 0);   \
        accz = __builtin_amdgcn_mfma_f32_16x16x32_f16(ha2, wZ2, accz, 0, 0, 0);   \
        accn = __builtin_amdgcn_mfma_f32_16x16x32_f16(ha2, wN2, accn, 0, 0, 0);   \
        accr = __builtin_amdgcn_mfma_f32_16x16x32_f16(ha3, wR3, accr, 0, 0, 0);   \
        accz = __builtin_amdgcn_mfma_f32_16x16x32_f16(ha3, wZ3, accz, 0, 0, 0);   \
        accn = __builtin_amdgcn_mfma_f32_16x16x32_f16(ha3, wN3, accn, 0, 0, 0);   \
        float ar = accr[0], az = accz[0], an = accn[0];                           \
        int tp = t + 2; if (tp > T_DIM - 1) tp = T_DIM - 1;                       \
        const float* gp = gxb + (size_t)tp * G_DIM + jl;                          \
        float nxr = gp[0], nxz = gp[128], nxn = gp[256];                          \
        float r  = sigmoid_f(CXR + ar + bhr);                                     \
        float z  = sigmoid_f(CXZ + az + bhz);                                     \
        float nn = tanh_f(CXN + r * (an + bhn));                                  \
        float hnew = nn + z * (h_prev - nn);                                      \
        h_prev = hnew;                                                            \
        if (fq == 0) {                                                            \
            ((_Float16*)&hbuf[PR ^ 1][0])[jl] = (_Float16)hnew;                   \
            if (WRITE_SEQ) seqb[(size_t)t * H_DIM + jl] = hnew;                   \
        }                                                                         \
        CXR = nxr; CXZ = nxz; CXN = nxn;                                          \
        FAST_BARRIER()                                                            \
    }

template<bool WRITE_SEQ>
__global__ __attribute__((amdgpu_flat_work_group_size(512, 512),
                          amdgpu_waves_per_eu(2, 2)))
void gru_scan_mfma_kernel(const float* __restrict__ gx,    // [B,T,3H] (incl b_ih)
                          const float* __restrict__ whh,   // [3H,H] this layer
                          const float* __restrict__ bhh,   // [3H]
                          const int*   __restrict__ lengths,
                          float* __restrict__ seq_out,     // [B,T,H] if WRITE_SEQ
                          float* __restrict__ final_out)   // [B,H]  if !WRITE_SEQ
{
    __shared__ __align__(16) uint32 hbuf[2][68];    // 128 f16 + pad, dbuf

    const int b   = blockIdx.x;
    const int tid = threadIdx.x;
    const int w   = tid >> 6;        // wave 0..7 -> j block
    const int ln  = tid & 63;
    const int fr  = ln & 15;         // j within block
    const int fq  = ln >> 4;         // k-subchunk 0..3 (replica group)
    const int jl  = w * 16 + fr;     // this lane's output element

    // resident B-fragments: gate g, chunk c -> W_hh[g*128 + jl][c*32 + fq*8 ..+8]
    f16x8 wR0, wR1, wR2, wR3, wZ0, wZ1, wZ2, wZ3, wN0, wN1, wN2, wN3;
    {
        const float* base = whh + (size_t)jl * H_DIM + fq * 8;
#define LOADW(dst, g, c)                                                          \
        {                                                                         \
            const float* wp = base + (size_t)(g) * 128 * H_DIM + (c) * 32;        \
            float4 v0 = *(const float4*)wp;                                       \
            float4 v1 = *(const float4*)(wp + 4);                                 \
            u32x4 u;                                                              \
            u.x = packf16(v0.x, v0.y); u.y = packf16(v0.z, v0.w);                 \
            u.z = packf16(v1.x, v1.y); u.w = packf16(v1.z, v1.w);                 \
            dst = __builtin_bit_cast(f16x8, u);                                   \
        }
        LOADW(wR0, 0, 0) LOADW(wR1, 0, 1) LOADW(wR2, 0, 2) LOADW(wR3, 0, 3)
        LOADW(wZ0, 1, 0) LOADW(wZ1, 1, 1) LOADW(wZ2, 1, 2) LOADW(wZ3, 1, 3)
        LOADW(wN0, 2, 0) LOADW(wN1, 2, 1) LOADW(wN2, 2, 2) LOADW(wN3, 2, 3)
#undef LOADW
    }

    const int len = lengths[b];
    const float* gxb = gx + (size_t)b * T_DIM * G_DIM;
    float* seqb = WRITE_SEQ ? (seq_out + (size_t)b * T_DIM * H_DIM) : nullptr;

    const float bhr = bhh[jl], bhz = bhh[jl + 128], bhn = bhh[jl + 256];

    // gx ping-pong prefetch (2 steps ahead); fq replicas load redundantly
    float exr = gxb[jl],         exz = gxb[jl + 128],         exn = gxb[jl + 256];
    float oxr = gxb[G_DIM + jl], oxz = gxb[G_DIM + jl + 128], oxn = gxb[G_DIM + jl + 256];

    for (int i = tid; i < 2 * 68; i += 512) ((uint32*)hbuf)[i] = 0u;
    __syncthreads();

    float h_prev = 0.0f;   // fp32 master copy of h[jl], identical across fq

    int t = 0;
    while (t < len) {      // len is block-uniform; barriers stay uniform
        SCAN_STEP(0, exr, exz, exn)
        ++t;
        if (t >= len) break;
        SCAN_STEP(1, oxr, oxz, oxn)
        ++t;
    }

    if (!WRITE_SEQ && fq == 0)
        final_out[(size_t)b * H_DIM + jl] = h_prev;
}

extern "C" void kernel_launch(void* const* d_in, const int* in_sizes, int n_in,
                              void* d_out, int out_size, void* d_ws, size_t ws_size,
                              hipStream_t stream)
{
    (void)in_sizes; (void)n_in; (void)out_size; (void)ws_size;
    const float* x      = (const float*)d_in[0];
    const float* w_proj = (const float*)d_in[1];
    const float* b_proj = (const float*)d_in[2];
    const float* w_ih   = (const float*)d_in[3];
    const float* w_hh   = (const float*)d_in[4];
    const float* b_ih   = (const float*)d_in[5];
    const float* b_hh   = (const float*)d_in[6];
    float* out = (float*)d_out;

    // ws: [0,64MB) out0/feat; [64MB,256MB) gx; [256MB,+256B) lengths;
    //     [256MB+4KB, +768KB) Wcomb; then bcomb (1.5KB)
    char*  ws      = (char*)d_ws;
    float* feat    = (float*)(ws);
    float* gxbuf   = (float*)(ws + 67108864ull);
    int*   lengths = (int*)  (ws + 268435456ull);
    float* Wcomb   = (float*)(ws + 268435456ull + 4096ull);
    float* bcomb   = Wcomb + (size_t)G_DIM * F_DIM;

    hipMemsetAsync(lengths, 0, B_DIM * sizeof(int), stream);

    // 0) fold projection into layer-0 gate weights: Wcomb = w_ih0 @ w_proj
    wcomb_kernel<<<192, 256, 0, stream>>>(w_ih, w_proj, b_proj, b_ih, Wcomb, bcomb);
    // 1) gx0 = x @ Wcomb^T + bcomb (+ lengths from x rowsums)  M=131072,K=512,N=384
    gemm_mfma_kernel<F_DIM, G_DIM, true>
        <<<dim3(1024, 3), 256, 0, stream>>>(x, Wcomb, bcomb, gxbuf, lengths);
    // 2) layer-0 scan -> out0 (feat buffer)
    gru_scan_mfma_kernel<true><<<B_DIM, 512, 0, stream>>>(
        gxbuf, w_hh, b_hh, lengths, feat, nullptr);
    // 3) gx1 = out0 @ w_ih[1]^T + b_ih[1]                      M=131072,K=128,N=384
    gemm_mfma_kernel<H_DIM, G_DIM, false>
        <<<dim3(1024, 3), 256, 0, stream>>>(feat, w_ih + G_DIM*H_DIM, b_ih + G_DIM, gxbuf, nullptr);
    // 4) layer-1 scan -> final top-layer state
    gru_scan_mfma_kernel<false><<<B_DIM, 512, 0, stream>>>(
        gxbuf, w_hh + G_DIM*H_DIM, b_hh + G_DIM, lengths, nullptr, out);
}

// Round 19
// 2783.679 us; speedup vs baseline: 1.0504x; 1.0504x over previous
//
#include <hip/hip_runtime.h>

#define B_DIM 64
#define T_DIM 2048
#define F_DIM 512
#define H_DIM 128
#define G_DIM 384  // 3*H

typedef _Float16 half2_t __attribute__((ext_vector_type(2)));
typedef _Float16 f16x8   __attribute__((ext_vector_type(8)));
typedef unsigned int uint32;
typedef uint32 u32x4 __attribute__((ext_vector_type(4)));
typedef short bf16x8 __attribute__((ext_vector_type(8)));
typedef float f32x4  __attribute__((ext_vector_type(4)));

__device__ __forceinline__ float sigmoid_f(float x) {
    return __fdividef(1.0f, 1.0f + __expf(-x));
}
__device__ __forceinline__ float tanh_f(float x) {
    return __fdividef(2.0f, 1.0f + __expf(-2.0f * x)) - 1.0f;
}

__device__ __forceinline__ uint32 packf16(float a, float b) {
    half2_t p; p.x = (_Float16)a; p.y = (_Float16)b;
    return __builtin_bit_cast(uint32, p);
}

__device__ __forceinline__ uint32 pk_bf16(float lo, float hi) {
    uint32 r;
    asm("v_cvt_pk_bf16_f32 %0, %1, %2" : "=v"(r) : "v"(lo), "v"(hi));
    return r;
}

#define FAST_BARRIER()                                                            \
    __builtin_amdgcn_sched_barrier(0);                                            \
    asm volatile("s_waitcnt lgkmcnt(0)" ::: "memory");                            \
    __builtin_amdgcn_s_barrier();                                                 \
    __builtin_amdgcn_sched_barrier(0);

// ---------------------------------------------------------------------------
// bf16 MFMA GEMM (R10-proven): used for the K=512 projection (+ lengths).
// ---------------------------------------------------------------------------
template<int KDIM, int NDIM, bool DO_LEN>
__global__ __launch_bounds__(256)
void gemm_mfma_kernel(const float* __restrict__ A, const float* __restrict__ W,
                      const float* __restrict__ bias, float* __restrict__ C,
                      int* __restrict__ lengths)
{
    constexpr int KSTEPS = KDIM / 32;
    constexpr int PAD = 40;
    __shared__ __align__(16) unsigned short At[128 * PAD];
    __shared__ __align__(16) unsigned short Bt[128 * PAD];

    const int tid = threadIdx.x;
    const int m0  = blockIdx.x * 128;
    const int n0  = blockIdx.y * 128;
    const int row = tid >> 1;
    const int kh  = tid & 1;

    const float* Ap = A + (size_t)(m0 + row) * KDIM + kh * 16;
    const float* Wp = W + (size_t)(n0 + row) * KDIM + kh * 16;

    float4 aPre[4], bPre[4];
#pragma unroll
    for (int q = 0; q < 4; ++q) {
        aPre[q] = *(const float4*)(Ap + q * 4);
        bPre[q] = *(const float4*)(Wp + q * 4);
    }

    f32x4 acc[4][4];
#pragma unroll
    for (int i = 0; i < 4; ++i)
#pragma unroll
        for (int j = 0; j < 4; ++j) acc[i][j] = (f32x4){0.f, 0.f, 0.f, 0.f};

    const int wv = tid >> 6;
    const int wm = (wv >> 1) * 64;
    const int wn = (wv & 1) * 64;
    const int ln = tid & 63;
    const int fr = ln & 15;
    const int fq = ln >> 4;

    float rowsum = 0.0f;

    for (int ks = 0; ks < KSTEPS; ++ks) {
        if (DO_LEN) {
#pragma unroll
            for (int q = 0; q < 4; ++q)
                rowsum += aPre[q].x + aPre[q].y + aPre[q].z + aPre[q].w;
        }
        {
            uint32* ad = (uint32*)&At[row * PAD + kh * 16];
            uint32* bd = (uint32*)&Bt[row * PAD + kh * 16];
            uint4 au, bu;
            au.x = pk_bf16(aPre[0].x, aPre[0].y); au.y = pk_bf16(aPre[0].z, aPre[0].w);
            au.z = pk_bf16(aPre[1].x, aPre[1].y); au.w = pk_bf16(aPre[1].z, aPre[1].w);
            *(uint4*)ad = au;
            au.x = pk_bf16(aPre[2].x, aPre[2].y); au.y = pk_bf16(aPre[2].z, aPre[2].w);
            au.z = pk_bf16(aPre[3].x, aPre[3].y); au.w = pk_bf16(aPre[3].z, aPre[3].w);
            *(uint4*)(ad + 4) = au;
            bu.x = pk_bf16(bPre[0].x, bPre[0].y); bu.y = pk_bf16(bPre[0].z, bPre[0].w);
            bu.z = pk_bf16(bPre[1].x, bPre[1].y); bu.w = pk_bf16(bPre[1].z, bPre[1].w);
            *(uint4*)bd = bu;
            bu.x = pk_bf16(bPre[2].x, bPre[2].y); bu.y = pk_bf16(bPre[2].z, bPre[2].w);
            bu.z = pk_bf16(bPre[3].x, bPre[3].y); bu.w = pk_bf16(bPre[3].z, bPre[3].w);
            *(uint4*)(bd + 4) = bu;
        }
        __syncthreads();
        if (ks + 1 < KSTEPS) {
#pragma unroll
            for (int q = 0; q < 4; ++q) {
                aPre[q] = *(const float4*)(Ap + (ks + 1) * 32 + q * 4);
                bPre[q] = *(const float4*)(Wp + (ks + 1) * 32 + q * 4);
            }
        }
        bf16x8 aF[4], bF[4];
#pragma unroll
        for (int i = 0; i < 4; ++i) {
            aF[i] = *(const bf16x8*)&At[(wm + i * 16 + fr) * PAD + fq * 8];
            bF[i] = *(const bf16x8*)&Bt[(wn + i * 16 + fr) * PAD + fq * 8];
        }
#pragma unroll
        for (int i = 0; i < 4; ++i)
#pragma unroll
            for (int j = 0; j < 4; ++j)
                acc[i][j] = __builtin_amdgcn_mfma_f32_16x16x32_bf16(
                                aF[i], bF[j], acc[i][j], 0, 0, 0);
        __syncthreads();
    }

#pragma unroll
    for (int i = 0; i < 4; ++i) {
#pragma unroll
        for (int j = 0; j < 4; ++j) {
            const int n = n0 + wn + j * 16 + fr;
            const float bn = bias[n];
            const int mbase = m0 + wm + i * 16 + fq * 4;
#pragma unroll
            for (int r = 0; r < 4; ++r)
                C[(size_t)(mbase + r) * NDIM + n] = acc[i][j][r] + bn;
        }
    }

    if (DO_LEN && blockIdx.y == 0) {
        rowsum += __shfl_xor(rowsum, 1);
        if (kh == 0 && rowsum != 0.0f)
            atomicAdd(&lengths[(m0 + row) >> 11], 1);
    }
}

// ---------------------------------------------------------------------------
// W-resident gx GEMM: C[M,384] = A[M,128] @ W[384,128]^T + bias.
// Grid (256, 3): block stages its W n-block [128][K=128] bf16 into LDS ONCE
// (4 kstep-chunks of [128][40], the proven 0-conflict geometry), then loops
// MT=4 M-tiles: prefetch next A-tile into regs during the 64 MFMAs (4 ksteps,
// barrier-free, both operands from LDS), 2 barriers per tile. 80KB LDS ->
// 2 blocks/CU; staging latency hidden by compute + cross-block overlap.
// ---------------------------------------------------------------------------
__global__ __launch_bounds__(256)
void gemm_gx_kernel(const float* __restrict__ A,    // [M,128]
                    const float* __restrict__ W,    // [384,128]
                    const float* __restrict__ bias, // [384]
                    float* __restrict__ C)          // [M,384]
{
    constexpr int MT = 4;
    __shared__ __align__(16) unsigned short Wt[4 * 128 * 40];  // [ks][row][40]
    __shared__ __align__(16) unsigned short At[4 * 128 * 40];

    const int tid = threadIdx.x;
    const int n0  = blockIdx.y * 128;
    const size_t m0base = (size_t)blockIdx.x * (MT * 128);

    const int r = tid >> 1;   // staged row 0..127
    const int h = tid & 1;    // k-half (64 floats)

    // ---- stage W once + A(0) ----
    {
        const float* wp = W + (size_t)(n0 + r) * H_DIM + h * 64;
        const float* ap = A + (m0base + r) * H_DIM + h * 64;
#pragma unroll
        for (int p = 0; p < 8; ++p) {
            const int kl = h * 64 + p * 8;
            const int ks = kl >> 5;
            const int fs = (kl & 31) >> 3;
            float4 w0 = *(const float4*)(wp + p * 8);
            float4 w1 = *(const float4*)(wp + p * 8 + 4);
            float4 a0 = *(const float4*)(ap + p * 8);
            float4 a1 = *(const float4*)(ap + p * 8 + 4);
            uint4 u;
            u.x = pk_bf16(w0.x, w0.y); u.y = pk_bf16(w0.z, w0.w);
            u.z = pk_bf16(w1.x, w1.y); u.w = pk_bf16(w1.z, w1.w);
            *(uint4*)&Wt[ks * 5120 + r * 40 + fs * 8] = u;
            u.x = pk_bf16(a0.x, a0.y); u.y = pk_bf16(a0.z, a0.w);
            u.z = pk_bf16(a1.x, a1.y); u.w = pk_bf16(a1.z, a1.w);
            *(uint4*)&At[ks * 5120 + r * 40 + fs * 8] = u;
        }
    }
    __syncthreads();

    const int wv = tid >> 6;
    const int wm = (wv >> 1) * 64;
    const int wn = (wv & 1) * 64;
    const int ln = tid & 63;
    const int fr = ln & 15;
    const int fq = ln >> 4;

    for (int mt = 0; mt < MT; ++mt) {
        float4 pre[16];
        if (mt + 1 < MT) {   // issue next A-tile loads; latency hides under MFMAs
            const float* ap = A + (m0base + (mt + 1) * 128 + r) * H_DIM + h * 64;
#pragma unroll
            for (int p = 0; p < 16; ++p) pre[p] = *(const float4*)(ap + p * 4);
        }

        f32x4 acc[4][4];
#pragma unroll
        for (int i = 0; i < 4; ++i)
#pragma unroll
            for (int j = 0; j < 4; ++j) acc[i][j] = (f32x4){0.f, 0.f, 0.f, 0.f};

#pragma unroll
        for (int ks = 0; ks < 4; ++ks) {
            bf16x8 aF[4], bF[4];
#pragma unroll
            for (int i = 0; i < 4; ++i) {
                aF[i] = *(const bf16x8*)&At[ks * 5120 + (wm + i * 16 + fr) * 40 + fq * 8];
                bF[i] = *(const bf16x8*)&Wt[ks * 5120 + (wn + i * 16 + fr) * 40 + fq * 8];
            }
#pragma unroll
            for (int i = 0; i < 4; ++i)
#pragma unroll
                for (int j = 0; j < 4; ++j)
                    acc[i][j] = __builtin_amdgcn_mfma_f32_16x16x32_bf16(
                                    aF[i], bF[j], acc[i][j], 0, 0, 0);
        }
        __syncthreads();                     // everyone done reading At
        if (mt + 1 < MT) {                   // write next tile (no reader yet)
#pragma unroll
            for (int p = 0; p < 8; ++p) {
                const int kl = h * 64 + p * 8;
                const int ks = kl >> 5;
                const int fs = (kl & 31) >> 3;
                uint4 u;
                u.x = pk_bf16(pre[2*p].x,   pre[2*p].y);
                u.y = pk_bf16(pre[2*p].z,   pre[2*p].w);
                u.z = pk_bf16(pre[2*p+1].x, pre[2*p+1].y);
                u.w = pk_bf16(pre[2*p+1].z, pre[2*p+1].w);
                *(uint4*)&At[ks * 5120 + r * 40 + fs * 8] = u;
            }
        }
        // store C(mt) — global only, overlaps the LDS writes above
#pragma unroll
        for (int i = 0; i < 4; ++i) {
#pragma unroll
            for (int j = 0; j < 4; ++j) {
                const int n = n0 + wn + j * 16 + fr;
                const float bn = bias[n];
                const size_t mb = m0base + mt * 128 + wm + i * 16 + fq * 4;
#pragma unroll
                for (int rr = 0; rr < 4; ++rr)
                    C[(mb + rr) * G_DIM + n] = acc[i][j][rr] + bn;
            }
        }
        if (mt + 1 < MT) __syncthreads();    // At(mt+1) ready
    }
}

// ---------------------------------------------------------------------------
// Barrier-minimal MFMA GRU scan (R16-proven). One block per batch element,
// 512 threads = 8 waves. Wave w owns j in [w*16, w*16+16): 12 chained
// mfma_f32_16x16x32_f16 (A = h broadcast) give every lane the complete K=128
// dot for its (j, gate) in acc[0]. Redundant gate math across fq replicas;
// fq==0 writes h' f16. ONE barrier per step. 48 resident u32 weights.
// ---------------------------------------------------------------------------
#define SCAN_STEP(PR, CXR, CXZ, CXN)                                              \
    {                                                                             \
        const _Float16* hb = (const _Float16*)&hbuf[PR][0];                       \
        f16x8 ha0 = *(const f16x8*)(hb + 0 * 32 + fq * 8);                        \
        f16x8 ha1 = *(const f16x8*)(hb + 1 * 32 + fq * 8);                        \
        f16x8 ha2 = *(const f16x8*)(hb + 2 * 32 + fq * 8);                        \
        f16x8 ha3 = *(const f16x8*)(hb + 3 * 32 + fq * 8);                        \
        f32x4 accr = (f32x4){0.f,0.f,0.f,0.f};                                    \
        f32x4 accz = (f32x4){0.f,0.f,0.f,0.f};                                    \
        f32x4 accn = (f32x4){0.f,0.f,0.f,0.f};                                    \
        accr = __builtin_amdgcn_mfma_f32_16x16x32_f16(ha0, wR0, accr, 0, 0, 0);   \
        accz = __builtin_amdgcn_mfma_f32_16x16x32_f16(ha0, wZ0, accz, 0, 0, 0);   \
        accn = __builtin_amdgcn_mfma_f32_16x16x32_f16(ha0, wN0, accn, 0, 0, 0);   \
        accr = __builtin_amdgcn_mfma_f32_16x16x32_f16(ha1, wR1, accr, 0, 0, 0);   \
        accz = __builtin_amdgcn_mfma_f32_16x16x32_f16(ha1, wZ1, accz, 0, 0, 0);   \
        accn = __builtin_amdgcn_mfma_f32_16x16x32_f16(ha1, wN1, accn, 0, 0, 0);   \
        accr = __builtin_amdgcn_mfma_f32_16x16x32_f16(ha2, wR2, accr, 0, 0, 0);   \
        accz = __builtin_amdgcn_mfma_f32_16x16x32_f16(ha2, wZ2, accz, 0, 0, 0);   \
        accn = __builtin_amdgcn_mfma_f32_16x16x32_f16(ha2, wN2, accn, 0, 0, 0);   \
        accr = __builtin_amdgcn_mfma_f32_16x16x32_f16(ha3, wR3, accr, 0, 0, 0);   \
        accz = __builtin_amdgcn_mfma_f32_16x16x32_f16(ha3, wZ3, accz, 0, 0, 0);   \
        accn = __builtin_amdgcn_mfma_f32_16x16x32_f16(ha3, wN3, accn, 0, 0, 0);   \
        float ar = accr[0], az = accz[0], an = accn[0];                           \
        int tp = t + 2; if (tp > T_DIM - 1) tp = T_DIM - 1;                       \
        const float* gp = gxb + (size_t)tp * G_DIM + jl;                          \
        float nxr = gp[0], nxz = gp[128], nxn = gp[256];                          \
        float r  = sigmoid_f(CXR + ar + bhr);                                     \
        float z  = sigmoid_f(CXZ + az + bhz);                                     \
        float nn = tanh_f(CXN + r * (an + bhn));                                  \
        float hnew = nn + z * (h_prev - nn);                                      \
        h_prev = hnew;                                                            \
        if (fq == 0) {                                                            \
            ((_Float16*)&hbuf[PR ^ 1][0])[jl] = (_Float16)hnew;                   \
            if (WRITE_SEQ) seqb[(size_t)t * H_DIM + jl] = hnew;                   \
        }                                                                         \
        CXR = nxr; CXZ = nxz; CXN = nxn;                                          \
        FAST_BARRIER()                                                            \
    }

template<bool WRITE_SEQ>
__global__ __attribute__((amdgpu_flat_work_group_size(512, 512),
                          amdgpu_waves_per_eu(2, 2)))
void gru_scan_mfma_kernel(const float* __restrict__ gx,    // [B,T,3H] (incl b_ih)
                          const float* __restrict__ whh,   // [3H,H] this layer
                          const float* __restrict__ bhh,   // [3H]
                          const int*   __restrict__ lengths,
                          float* __restrict__ seq_out,     // [B,T,H] if WRITE_SEQ
                          float* __restrict__ final_out)   // [B,H]  if !WRITE_SEQ
{
    __shared__ __align__(16) uint32 hbuf[2][68];    // 128 f16 + pad, dbuf

    const int b   = blockIdx.x;
    const int tid = threadIdx.x;
    const int w   = tid >> 6;        // wave 0..7 -> j block
    const int ln  = tid & 63;
    const int fr  = ln & 15;         // j within block
    const int fq  = ln >> 4;         // k-subchunk 0..3 (replica group)
    const int jl  = w * 16 + fr;     // this lane's output element

    // resident B-fragments: gate g, chunk c -> W_hh[g*128 + jl][c*32 + fq*8 ..+8]
    f16x8 wR0, wR1, wR2, wR3, wZ0, wZ1, wZ2, wZ3, wN0, wN1, wN2, wN3;
    {
        const float* base = whh + (size_t)jl * H_DIM + fq * 8;
#define LOADW(dst, g, c)                                                          \
        {                                                                         \
            const float* wp = base + (size_t)(g) * 128 * H_DIM + (c) * 32;        \
            float4 v0 = *(const float4*)wp;                                       \
            float4 v1 = *(const float4*)(wp + 4);                                 \
            u32x4 u;                                                              \
            u.x = packf16(v0.x, v0.y); u.y = packf16(v0.z, v0.w);                 \
            u.z = packf16(v1.x, v1.y); u.w = packf16(v1.z, v1.w);                 \
            dst = __builtin_bit_cast(f16x8, u);                                   \
        }
        LOADW(wR0, 0, 0) LOADW(wR1, 0, 1) LOADW(wR2, 0, 2) LOADW(wR3, 0, 3)
        LOADW(wZ0, 1, 0) LOADW(wZ1, 1, 1) LOADW(wZ2, 1, 2) LOADW(wZ3, 1, 3)
        LOADW(wN0, 2, 0) LOADW(wN1, 2, 1) LOADW(wN2, 2, 2) LOADW(wN3, 2, 3)
#undef LOADW
    }

    const int len = lengths[b];
    const float* gxb = gx + (size_t)b * T_DIM * G_DIM;
    float* seqb = WRITE_SEQ ? (seq_out + (size_t)b * T_DIM * H_DIM) : nullptr;

    const float bhr = bhh[jl], bhz = bhh[jl + 128], bhn = bhh[jl + 256];

    // gx ping-pong prefetch (2 steps ahead); fq replicas load redundantly
    float exr = gxb[jl],         exz = gxb[jl + 128],         exn = gxb[jl + 256];
    float oxr = gxb[G_DIM + jl], oxz = gxb[G_DIM + jl + 128], oxn = gxb[G_DIM + jl + 256];

    for (int i = tid; i < 2 * 68; i += 512) ((uint32*)hbuf)[i] = 0u;
    __syncthreads();

    float h_prev = 0.0f;   // fp32 master copy of h[jl], identical across fq

    int t = 0;
    while (t < len) {      // len is block-uniform; barriers stay uniform
        SCAN_STEP(0, exr, exz, exn)
        ++t;
        if (t >= len) break;
        SCAN_STEP(1, oxr, oxz, oxn)
        ++t;
    }

    if (!WRITE_SEQ && fq == 0)
        final_out[(size_t)b * H_DIM + jl] = h_prev;
}

extern "C" void kernel_launch(void* const* d_in, const int* in_sizes, int n_in,
                              void* d_out, int out_size, void* d_ws, size_t ws_size,
                              hipStream_t stream)
{
    (void)in_sizes; (void)n_in; (void)out_size; (void)ws_size;
    const float* x      = (const float*)d_in[0];
    const float* w_proj = (const float*)d_in[1];
    const float* b_proj = (const float*)d_in[2];
    const float* w_ih   = (const float*)d_in[3];
    const float* w_hh   = (const float*)d_in[4];
    const float* b_ih   = (const float*)d_in[5];
    const float* b_hh   = (const float*)d_in[6];
    float* out = (float*)d_out;

    char*  ws      = (char*)d_ws;
    float* feat    = (float*)(ws);
    float* gxbuf   = (float*)(ws + 67108864ull);
    int*   lengths = (int*)  (ws + 268435456ull);

    hipMemsetAsync(lengths, 0, B_DIM * sizeof(int), stream);

    const int M = B_DIM * T_DIM;
    // 1) feat = x @ w_proj^T + b_proj (+ lengths)   M=131072, N=128, K=512
    gemm_mfma_kernel<F_DIM, H_DIM, true>
        <<<dim3(M / 128, 1), 256, 0, stream>>>(x, w_proj, b_proj, feat, lengths);
    // 2) gx0 = feat @ w_ih[0]^T + b_ih[0]           W-resident, MT=4
    gemm_gx_kernel<<<dim3(M / 512, 3), 256, 0, stream>>>(feat, w_ih, b_ih, gxbuf);
    // 3) layer-0 scan -> out0 (feat buffer)
    gru_scan_mfma_kernel<true><<<B_DIM, 512, 0, stream>>>(
        gxbuf, w_hh, b_hh, lengths, feat, nullptr);
    // 4) gx1 = out0 @ w_ih[1]^T + b_ih[1]           W-resident, MT=4
    gemm_gx_kernel<<<dim3(M / 512, 3), 256, 0, stream>>>(
        feat, w_ih + G_DIM * H_DIM, b_ih + G_DIM, gxbuf);
    // 5) layer-1 scan -> final top-layer state
    gru_scan_mfma_kernel<false><<<B_DIM, 512, 0, stream>>>(
        gxbuf, w_hh + G_DIM * H_DIM, b_hh + G_DIM, lengths, nullptr, out);
}